// Round 7
// baseline (264.600 us; speedup 1.0000x reference)
//
#include <hip/hip_runtime.h>

typedef unsigned short u16;
typedef unsigned int u32;
typedef __bf16 bf16x8 __attribute__((ext_vector_type(8)));
typedef float floatx4 __attribute__((ext_vector_type(4)));

// raw v_exp_f32 (2^x). Score scale has log2(e) folded in (fused RoPE epilogue).
#if __has_builtin(__builtin_amdgcn_exp2f)
#define EXP2F(x) __builtin_amdgcn_exp2f(x)
#else
#define EXP2F(x) __expf((x) * 0.6931471805599453f)
#endif

// B=4, S=1024, DIM=2048, HQ=16, HKV=4, HD=128, G=4
__device__ __forceinline__ u16 f2bf(float x) {
  union { float f; u32 u; } v; v.f = x;
  u32 r = v.u + 0x7fffu + ((v.u >> 16) & 1u);   // RNE
  return (u16)(r >> 16);
}
__device__ __forceinline__ float bf2f(u16 x) {
  union { float f; u32 u; } v; v.u = ((u32)x) << 16;
  return v.f;
}

// async global->LDS, 16B per lane. LDS dest must be wave-uniform base + lane*16.
__device__ __forceinline__ void gl_lds16(const u16* g, u16* l) {
  __builtin_amdgcn_global_load_lds((const __attribute__((address_space(1))) void*)g,
                                   (__attribute__((address_space(3))) void*)l, 16, 0, 0);
}

// ---------------- fused f32 -> bf16 conversion of all 5 tensors ----------------
// Blocks >= 18432 generate the RoPE cos/sin table (1024 x 64 float2):
// csnT[s*64+p] = (cos th, sin th). Table feeds gemm_qkv's fused-RoPE epilogue.
// R6 FAILURE NOTE: a head-dim de-interleave permutation of wq/wk rows (to make
// RoPE pairs lane-local in the MFMA C-layout) failed verification (absmax
// 0.043 vs 0.0156) despite multiple independent derivations checking out.
// Do NOT re-attempt without an offline element-level q/k dump vs reference.
__global__ __launch_bounds__(256) void cvt_all(const float* __restrict__ x,
                                               const float* __restrict__ wq,
                                               const float* __restrict__ wk,
                                               const float* __restrict__ wv,
                                               const float* __restrict__ wo,
                                               const float* __restrict__ fr,
                                               u16* __restrict__ xb, u16* __restrict__ wqb,
                                               u16* __restrict__ wkb, u16* __restrict__ wvb,
                                               u16* __restrict__ wob,
                                               float2* __restrict__ csnT) {
  int i = blockIdx.x * 256 + threadIdx.x;  // float4 index
  if (i >= 4718592) {                       // rope table: 65536 angles
    int idx = i - 4718592;
    float sn, cs;
    sincosf(fr[idx], &sn, &cs);
    csnT[idx] = make_float2(cs, sn);
    return;
  }
  const float* s; u16* d; int off;
  if (i < 2097152)      { s = x;  d = xb;  off = 0; }
  else if (i < 3145728) { s = wq; d = wqb; off = 2097152; }
  else if (i < 3407872) { s = wk; d = wkb; off = 3145728; }
  else if (i < 3670016) { s = wv; d = wvb; off = 3407872; }
  else                  { s = wo; d = wob; off = 3670016; }
  i -= off;
  float4 v = ((const float4*)s)[i];
  uint2 o;
  o.x = (u32)f2bf(v.x) | ((u32)f2bf(v.y) << 16);
  o.y = (u32)f2bf(v.z) | ((u32)f2bf(v.w) << 16);
  ((uint2*)d)[i] = o;
}

// ---------------- shared GEMM core: 128x128 tile, K=2048, BK=64, async staging --
// PROVEN R3 core: 831 TF / 35% MfmaUtil = the documented ~900 TF ceiling of the
// 2-barrier-per-K-step structure, with 3 blocks/CU giving cross-block overlap.
// R4 REGRESSION NOTE: an 8-phase counted-vmcnt port (128x256, 144KB LDS, 1
// block/CU, 384 blocks) HALVED throughput (120us, MfmaUtil 16.7%): two uneven
// dispatch rounds + single-block barrier convoy with only 8 MFMA/wave/phase.
// Counted-vmcnt needs the full m201 geometry (2-deep halftile pipeline,
// 16 MFMA/phase, exact-packed grid); do not graft it onto this tile shape.
// LDS layout XOR-swizzled: LDS(row, chunk) holds global(row, chunk ^ (row&7)),
// chunk = 8 u16 = 16 B. Kills the 16-way ds_read_b128 bank conflicts.
__device__ __forceinline__ void gemm_core(const u16* __restrict__ A, const u16* __restrict__ Bw,
                                          u16* sA, u16* sB, int m0, int n0,
                                          floatx4 acc[4][4]) {
  const int tid = threadIdx.x;
  const int wave = tid >> 6, lane = tid & 63;
  const int quad = lane >> 4, l16 = lane & 15;
  const int wm = (wave >> 1) * 64, wn = (wave & 1) * 64;
  const int srow = wave * 8 + (lane >> 3);
  // swizzled global source chunk for this lane's LDS slot (chunk = lane&7, row&7 = (lane>>3)&7)
  const int scol = (((lane & 7) ^ ((lane >> 3) & 7)) * 8);
  const int lds_off = wave * 512 + lane * 8;
  const int swA = (l16 & 7);  // read-side swizzle key (row&7 for MFMA fragment rows)
  for (int k0 = 0; k0 < 2048; k0 += 64) {
    __syncthreads();
    #pragma unroll
    for (int c = 0; c < 4; c++) {
      gl_lds16(A + (size_t)(m0 + c * 32 + srow) * 2048 + k0 + scol, sA + c * 2048 + lds_off);
      gl_lds16(Bw + (size_t)(n0 + c * 32 + srow) * 2048 + k0 + scol, sB + c * 2048 + lds_off);
    }
    __syncthreads();
    #pragma unroll
    for (int ks = 0; ks < 64; ks += 32) {
      const int pc = ((((ks >> 3) + quad) ^ swA) << 3);  // physical chunk*8
      bf16x8 af[4], bw[4];
      #pragma unroll
      for (int i = 0; i < 4; i++)
        af[i] = *(const bf16x8*)&sA[(wm + i * 16 + l16) * 64 + pc];
      #pragma unroll
      for (int j = 0; j < 4; j++)
        bw[j] = *(const bf16x8*)&sB[(wn + j * 16 + l16) * 64 + pc];
      #pragma unroll
      for (int i = 0; i < 4; i++)
        #pragma unroll
        for (int j = 0; j < 4; j++)
          acc[i][j] = __builtin_amdgcn_mfma_f32_16x16x32_bf16(af[i], bw[j], acc[i][j], 0, 0, 0);
    }
  }
}

// ---------------- fused QKV projection GEMM + fused RoPE epilogue ----------------
// RoPE fused (rope_both deleted). Pair (even col, odd col) sits in adjacent
// lanes (l16 even/odd). R7 epilogue: shfl_xor FIRST (all lanes active, partner
// value well-defined), then ONLY EVEN lanes load the cos/sin table entry,
// compute BOTH rotated elements, and store one packed u32 (re | im<<16) --
// byte-identical to R5's two u16 stores, but 32 table loads + 32 stores per
// thread instead of 64 + 64. q additionally scaled by (1/sqrt(128))*log2(e).
__global__ __launch_bounds__(256, 3) void gemm_qkv(const u16* __restrict__ xb,
                                                   const u16* __restrict__ wqb,
                                                   const u16* __restrict__ wkb,
                                                   const u16* __restrict__ wvb,
                                                   const float2* __restrict__ csnT,
                                                   u16* __restrict__ qb, u16* __restrict__ kb,
                                                   u16* __restrict__ vtb) {
  __shared__ __align__(16) u16 sA[128 * 64];
  __shared__ __align__(16) u16 sB[128 * 64];
  const int by = blockIdx.y;
  const u16* Bw; int n0, mode;
  if (by < 16)      { Bw = wqb; n0 = by * 128;        mode = 0; }
  else if (by < 20) { Bw = wkb; n0 = (by - 16) * 128; mode = 1; }
  else              { Bw = wvb; n0 = (by - 20) * 128; mode = 2; }
  const int m0 = blockIdx.x * 128;
  floatx4 acc[4][4] = {};
  gemm_core(xb, Bw, sA, sB, m0, n0, acc);
  const int tid = threadIdx.x;
  const int wave = tid >> 6, lane = tid & 63;
  const int quad = lane >> 4, l16 = lane & 15;
  const int wm = (wave >> 1) * 64, wn = (wave & 1) * 64;
  if (mode < 2) {
    const float QS = 0.08838834764831845f * 1.4426950408889634f;
    #pragma unroll
    for (int i = 0; i < 4; i++) {
      #pragma unroll
      for (int j = 0; j < 4; j++) {
        const int colw = wn + j * 16 + l16;     // col within head (0..127)
        const int p = colw >> 1;
        const int col = n0 + colw;
        #pragma unroll
        for (int r = 0; r < 4; r++) {
          const int m = m0 + wm + i * 16 + quad * 4 + r;
          const float val = acc[i][j][r];
          const float other = __shfl_xor(val, 1);  // all lanes; before divergence
          if (!(l16 & 1)) {                        // even lane owns the pair
            const float2 cs = csnT[(m & 1023) * 64 + p];
            float re = val * cs.x - other * cs.y;  // e' = e*cos - o*sin
            float im = val * cs.y + other * cs.x;  // o' = e*sin + o*cos
            if (mode == 0) { re *= QS; im *= QS; }
            const u32 w = (u32)f2bf(re) | ((u32)f2bf(im) << 16);
            if (mode == 0) *(u32*)(qb + (size_t)m * 2048 + col) = w;
            else           *(u32*)(kb + (size_t)m * 512 + col) = w;
          }
        }
      }
    }
  } else {
    #pragma unroll
    for (int i = 0; i < 4; i++) {
      #pragma unroll
      for (int j = 0; j < 4; j++) {
        const int row0 = m0 + wm + i * 16 + quad * 4;
        const int col = n0 + wn + j * 16 + l16;
        #pragma unroll
        for (int r = 0; r < 4; r++) {
          const int m = row0 + r;
          const u16 v16 = f2bf(acc[i][j][r]);
          int bb = m >> 10, sI = m & 1023, kvh = col >> 7, hd = col & 127;
          vtb[((size_t)((bb * 4 + kvh) * 128 + hd)) * 1024 + sI] = v16;
        }
      }
    }
  }
}

// ---------------- output projection GEMM (fp32 out) ----------------
__global__ __launch_bounds__(256, 3) void gemm_out(const u16* __restrict__ ob,
                                                   const u16* __restrict__ wob,
                                                   float* __restrict__ Cf) {
  __shared__ __align__(16) u16 sA[128 * 64];
  __shared__ __align__(16) u16 sB[128 * 64];
  const int m0 = blockIdx.x * 128, n0 = blockIdx.y * 128;
  floatx4 acc[4][4] = {};
  gemm_core(ob, wob, sA, sB, m0, n0, acc);
  const int tid = threadIdx.x;
  const int wave = tid >> 6, lane = tid & 63;
  const int quad = lane >> 4, l16 = lane & 15;
  const int wm = (wave >> 1) * 64, wn = (wave & 1) * 64;
  #pragma unroll
  for (int i = 0; i < 4; i++) {
    #pragma unroll
    for (int j = 0; j < 4; j++) {
      const int row0 = m0 + wm + i * 16 + quad * 4;
      const int col = n0 + wn + j * 16 + l16;
      #pragma unroll
      for (int r = 0; r < 4; r++)
        Cf[(size_t)(row0 + r) * 2048 + col] = acc[i][j][r];
    }
  }
}

// ---------------- O store: per-wave softmax-denominator normalize ----------------
__device__ __forceinline__ void store_out(u16* __restrict__ obaseHead, int qr0,
                                          floatx4 (&o_acc)[2][8], float (&l_part)[2],
                                          int quad, int l16) {
  #pragma unroll
  for (int i = 0; i < 2; i++) {
    float lr = l_part[i];
    lr += __shfl_xor(lr, 16);
    lr += __shfl_xor(lr, 32);
    // lane with l16=x (quad 0) now holds row total for qrow i*16+x
    #pragma unroll
    for (int r = 0; r < 4; r++) {
      const float inv = 1.f / __shfl(lr, quad * 4 + r);
      const int row = qr0 + i * 16 + quad * 4 + r;
      #pragma unroll
      for (int j = 0; j < 8; j++)
        obaseHead[(size_t)row * 2048 + j * 16 + l16] = f2bf(o_acc[i][j][r] * inv);
    }
  }
}

// ---------------- flash attention, LDS-staged K/V (verified R3) ----------------
// Block (256 thr = 4 waves) = one (b,kv) group x one 64-row seq-block x 2 of the
// 4 GQA query heads; all 4 waves share staged K/V tiles (L2 traffic /4).
// K double-buffered, V single-buffered, 2 barriers/tile, XOR-swizzled both sides.
__global__ __launch_bounds__(256)
__attribute__((amdgpu_waves_per_eu(2, 2)))
void flash_attn(const u16* __restrict__ q,
                const u16* __restrict__ k,
                const u16* __restrict__ vt,
                u16* __restrict__ o) {
  __shared__ __align__(16) u16 sK[2][64 * 128];  // 2 x 16 KB, chunk-swizzled
  __shared__ __align__(16) u16 sV[128 * 64];     // 16 KB (V^T: hd rows x 64 keys)
  __shared__ __align__(16) u16 sP[4][32 * 64];   // per-wave P, 4 KB each
  const int tid = threadIdx.x;
  const int wave = tid >> 6, lane = tid & 63;
  const int quad = lane >> 4, l16 = lane & 15;
  const int bi = blockIdx.x;
  const int bkv = bi & 15;                 // b*4 + kv
  const int b = bkv >> 2, kv = bkv & 3;
  const int hp = (bi >> 4) & 1;            // which pair of the 4 GQA q-heads
  const int u = bi >> 5;                   // 0..15
  const int m = (u < 8) ? u : 23 - u;      // seq-block 0..15; pairs (m,15-m)/CU
  const int qh = kv * 4 + hp * 2 + (wave >> 1);
  const int qr0 = m * 64 + (wave & 1) * 32;

  const u16* qbase = q + (size_t)b * 2097152 + qh * 128;
  const u16* vbase = vt + (size_t)(b * 4 + kv) * 131072;
  u16* obase = o + (size_t)b * 2097152 + qh * 128;
  u16* myP = &sP[wave][0];

  // ---- Q fragments in registers (rows qr0+i*16+l16, k = ks*32+quad*8) ----
  bf16x8 aq[2][4];
  #pragma unroll
  for (int i = 0; i < 2; i++)
    #pragma unroll
    for (int ks = 0; ks < 4; ks++)
      aq[i][ks] = *(const bf16x8*)(qbase + (size_t)(qr0 + i * 16 + l16) * 2048 + ks * 32 + quad * 8);

  floatx4 o_acc[2][8];
  float l_part[2];
  const floatx4 vzero = {0.f, 0.f, 0.f, 0.f};
  #pragma unroll
  for (int i = 0; i < 2; i++) {
    l_part[i] = 0.f;
    #pragma unroll
    for (int j = 0; j < 8; j++) o_acc[i][j] = vzero;
  }

  // ---- staging helpers: 256 threads x 4 x 16B cover one 16 KB tile ----
  // K tile (64 rows x 16 chunks): slot (r,c) holds global chunk c^(r&7).
  #define STAGE_K(T, PAR)                                                         \
    {                                                                             \
      const u16* kb_t = k + (size_t)(b * 1024 + (T) * 64) * 512 + kv * 128;       \
      _Pragma("unroll")                                                           \
      for (int v = 0; v < 4; v++) {                                               \
        int ci = v * 256 + tid;                                                   \
        int r = ci >> 4, c = ci & 15;                                             \
        gl_lds16(kb_t + r * 512 + ((c ^ (r & 7)) << 3), &sK[PAR][ci * 8]);        \
      }                                                                           \
    }
  // V tile (128 rows x 8 chunks): slot (r,c) holds global chunk c^(r&7).
  #define STAGE_V(T)                                                              \
    {                                                                             \
      _Pragma("unroll")                                                           \
      for (int v = 0; v < 4; v++) {                                               \
        int ci = v * 256 + tid;                                                   \
        int r = ci >> 3, c = ci & 7;                                              \
        gl_lds16(vbase + r * 1024 + (T) * 64 + ((c ^ (r & 7)) << 3), &sV[ci * 8]); \
      }                                                                           \
    }

  STAGE_K(0, 0);
  __syncthreads();  // K[0] staged (barrier implies vmcnt(0) drain)

  for (int t = 0; t <= m; t++) {
    // issue V[t] + K[t+1]; latency hides under QK+softmax
    STAGE_V(t);
    if (t < m) STAGE_K(t + 1, (t + 1) & 1);

    // ---- S^T = K Q^T from LDS K buffer (1-deep fragment ping-pong) ----
    const u16* kcur = &sK[t & 1][0];
    floatx4 s_acc[4][2];
    #pragma unroll
    for (int j = 0; j < 4; j++)
      #pragma unroll
      for (int i = 0; i < 2; i++) s_acc[j][i] = vzero;
    bf16x8 bkA[4], bkB[4];
    #pragma unroll
    for (int j = 0; j < 4; j++) {
      const int R = j * 16 + l16;
      bkA[j] = *(const bf16x8*)&kcur[R * 128 + ((quad ^ (R & 7)) << 3)];
    }
    #pragma unroll
    for (int ks = 0; ks < 4; ks++) {
      bf16x8* cur = (ks & 1) ? bkB : bkA;  // static after full unroll
      bf16x8* nxt = (ks & 1) ? bkA : bkB;
      if (ks < 3) {
        #pragma unroll
        for (int j = 0; j < 4; j++) {
          const int R = j * 16 + l16;
          nxt[j] = *(const bf16x8*)&kcur[R * 128 + ((((ks + 1) * 4 + quad) ^ (R & 7)) << 3)];
        }
      }
      #pragma unroll
      for (int j = 0; j < 4; j++)
        #pragma unroll
        for (int i = 0; i < 2; i++)
          s_acc[j][i] = __builtin_amdgcn_mfma_f32_16x16x32_bf16(cur[j], aq[i][ks], s_acc[j][i], 0, 0, 0);
    }

    // ---- no-max softmax: p = exp2(s); mask only on the diagonal tile ----
    const bool nomask = (t < m);
    #pragma unroll
    for (int i = 0; i < 2; i++) {
      const int qrow = qr0 + i * 16 + l16;
      #pragma unroll
      for (int j = 0; j < 4; j++) {
        const int key0 = t * 64 + j * 16 + quad * 4;
        float e0, e1, e2, e3;
        if (nomask) {
          e0 = EXP2F(s_acc[j][i][0]);
          e1 = EXP2F(s_acc[j][i][1]);
          e2 = EXP2F(s_acc[j][i][2]);
          e3 = EXP2F(s_acc[j][i][3]);
        } else {
          e0 = (key0 + 0 <= qrow) ? EXP2F(s_acc[j][i][0]) : 0.f;
          e1 = (key0 + 1 <= qrow) ? EXP2F(s_acc[j][i][1]) : 0.f;
          e2 = (key0 + 2 <= qrow) ? EXP2F(s_acc[j][i][2]) : 0.f;
          e3 = (key0 + 3 <= qrow) ? EXP2F(s_acc[j][i][3]) : 0.f;
        }
        l_part[i] += (e0 + e1) + (e2 + e3);
        uint2 w;
        w.x = (u32)f2bf(e0) | ((u32)f2bf(e1) << 16);
        w.y = (u32)f2bf(e2) | ((u32)f2bf(e3) << 16);
        const int ri = i * 16 + l16;
        // 8B write at logical chunk 2j+(quad>>1), half quad&1, swizzled
        *(uint2*)&myP[ri * 64 + (((2 * j + (quad >> 1)) ^ (ri & 7)) << 3) + (quad & 1) * 4] = w;
      }
    }

    __syncthreads();  // V[t] (and K[t+1]) arrived; all waves' QK reads done

    // ---- O += P V from LDS V buffer ----
    #pragma unroll
    for (int ks2 = 0; ks2 < 2; ks2++) {
      bf16x8 ap[2], bvf[8];
      #pragma unroll
      for (int j2 = 0; j2 < 8; j2++) {
        const int R = j2 * 16 + l16;
        bvf[j2] = *(const bf16x8*)&sV[R * 64 + (((ks2 * 4 + quad) ^ (R & 7)) << 3)];
      }
      #pragma unroll
      for (int i = 0; i < 2; i++) {
        const int ri = i * 16 + l16;
        ap[i] = *(const bf16x8*)&myP[ri * 64 + (((ks2 * 4 + quad) ^ (ri & 7)) << 3)];
      }
      #pragma unroll
      for (int i = 0; i < 2; i++)
        #pragma unroll
        for (int j2 = 0; j2 < 8; j2++)
          o_acc[i][j2] = __builtin_amdgcn_mfma_f32_16x16x32_bf16(ap[i], bvf[j2], o_acc[i][j2], 0, 0, 0);
    }

    __syncthreads();  // protect sV (and sK parity slot) before next stage
  }

  store_out(obase, qr0, o_acc, l_part, quad, l16);
  #undef STAGE_K
  #undef STAGE_V
}

extern "C" void kernel_launch(void* const* d_in, const int* in_sizes, int n_in,
                              void* d_out, int out_size, void* d_ws, size_t ws_size,
                              hipStream_t stream) {
  const float* x  = (const float*)d_in[0];
  const float* fr = (const float*)d_in[2];
  const float* wq = (const float*)d_in[4];
  const float* wk = (const float*)d_in[5];
  const float* wv = (const float*)d_in[6];
  const float* wo = (const float*)d_in[7];
  float* out = (float*)d_out;

  char* ws = (char*)d_ws;
  u16* xb  = (u16*)(ws + 0);           // 4096x2048        16.78 MB
  u16* wqb = (u16*)(ws + 16777216);    // 2048x2048         8.39 MB
  u16* wkb = (u16*)(ws + 25165824);    //  512x2048         2.10 MB
  u16* wvb = (u16*)(ws + 27262976);    //  512x2048         2.10 MB
  u16* wob = (u16*)(ws + 29360128);    // 2048x2048         8.39 MB
  u16* qb  = (u16*)(ws + 37748736);    // [B,S,16,128]     16.78 MB
  u16* kb  = (u16*)(ws + 54525952);    // [B,S,4,128]       4.19 MB
  u16* vtb = (u16*)(ws + 58720256);    // [B,4,128,S]       4.19 MB
  u16* ob  = (u16*)(ws + 62914560);    // [B,S,16,128]     16.78 MB
  // RoPE cos/sin table overlaps the FIRST 512 KB of ob: written by cvt_all,
  // read by gemm_qkv, and only AFTERWARDS does flash_attn overwrite ob.
  float2* csnT = (float2*)(ws + 62914560);

  cvt_all<<<18688, 256, 0, stream>>>(x, wq, wk, wv, wo, fr, xb, wqb, wkb, wvb, wob, csnT);
  gemm_qkv<<<dim3(32, 24), 256, 0, stream>>>(xb, wqb, wkb, wvb, csnT, qb, kb, vtb);
  flash_attn<<<512, 256, 0, stream>>>(qb, kb, vtb, ob);
  gemm_out<<<dim3(32, 16), 256, 0, stream>>>(ob, wob, out);
}

// Round 8
// 256.552 us; speedup vs baseline: 1.0314x; 1.0314x over previous
//
#include <hip/hip_runtime.h>

typedef unsigned short u16;
typedef unsigned int u32;
typedef __bf16 bf16x8 __attribute__((ext_vector_type(8)));
typedef float floatx4 __attribute__((ext_vector_type(4)));

// raw v_exp_f32 (2^x). Score scale has log2(e) folded in (fused RoPE epilogue).
#if __has_builtin(__builtin_amdgcn_exp2f)
#define EXP2F(x) __builtin_amdgcn_exp2f(x)
#else
#define EXP2F(x) __expf((x) * 0.6931471805599453f)
#endif

// B=4, S=1024, DIM=2048, HQ=16, HKV=4, HD=128, G=4
__device__ __forceinline__ u16 f2bf(float x) {
  union { float f; u32 u; } v; v.f = x;
  u32 r = v.u + 0x7fffu + ((v.u >> 16) & 1u);   // RNE
  return (u16)(r >> 16);
}
__device__ __forceinline__ float bf2f(u16 x) {
  union { float f; u32 u; } v; v.u = ((u32)x) << 16;
  return v.f;
}

// async global->LDS, 16B per lane. LDS dest must be wave-uniform base + lane*16.
__device__ __forceinline__ void gl_lds16(const u16* g, u16* l) {
  __builtin_amdgcn_global_load_lds((const __attribute__((address_space(1))) void*)g,
                                   (__attribute__((address_space(3))) void*)l, 16, 0, 0);
}

// ---------------- fused f32 -> bf16 conversion of all 5 tensors ----------------
// Blocks >= 18432 generate the RoPE cos/sin table (1024 x 64 float2):
// csnT[s*64+p] = (cos th, sin th). Table feeds gemm_qkv's fused-RoPE epilogue.
// R6 FAILURE NOTE: head-dim de-interleave permutation of wq/wk failed absmax
// (0.043); do NOT re-attempt without offline element-level q/k dump.
// R7 REGRESSION NOTE: "even-lane-only" RoPE epilogue (divergent dedup) cost
// +11.7us on gemm_qkv vs R5's uniform all-lanes version: 64 exec-mask toggles
// around the load/FMA/store clusters beat the saved loads. Keep epilogues
// lane-uniform even if redundant.
__global__ __launch_bounds__(256) void cvt_all(const float* __restrict__ x,
                                               const float* __restrict__ wq,
                                               const float* __restrict__ wk,
                                               const float* __restrict__ wv,
                                               const float* __restrict__ wo,
                                               const float* __restrict__ fr,
                                               u16* __restrict__ xb, u16* __restrict__ wqb,
                                               u16* __restrict__ wkb, u16* __restrict__ wvb,
                                               u16* __restrict__ wob,
                                               float2* __restrict__ csnT) {
  int i = blockIdx.x * 256 + threadIdx.x;  // float4 index
  if (i >= 4718592) {                       // rope table: 65536 angles
    int idx = i - 4718592;
    float sn, cs;
    sincosf(fr[idx], &sn, &cs);
    csnT[idx] = make_float2(cs, sn);
    return;
  }
  const float* s; u16* d; int off;
  if (i < 2097152)      { s = x;  d = xb;  off = 0; }
  else if (i < 3145728) { s = wq; d = wqb; off = 2097152; }
  else if (i < 3407872) { s = wk; d = wkb; off = 3145728; }
  else if (i < 3670016) { s = wv; d = wvb; off = 3407872; }
  else                  { s = wo; d = wob; off = 3670016; }
  i -= off;
  float4 v = ((const float4*)s)[i];
  uint2 o;
  o.x = (u32)f2bf(v.x) | ((u32)f2bf(v.y) << 16);
  o.y = (u32)f2bf(v.z) | ((u32)f2bf(v.w) << 16);
  ((uint2*)d)[i] = o;
}

// ---------------- shared GEMM core: 128x128 tile, K=2048, BK=64, async staging --
// PROVEN R3 core: 831 TF / 35% MfmaUtil (2-barrier structure, 3 blocks/CU).
// R4 REGRESSION NOTE: 8-phase counted-vmcnt port at wrong geometry halved
// throughput; don't graft counted-vmcnt onto this tile shape.
// LDS XOR-swizzled: LDS(row, chunk) holds global(row, chunk ^ (row&7)).
__device__ __forceinline__ void gemm_core(const u16* __restrict__ A, const u16* __restrict__ Bw,
                                          u16* sA, u16* sB, int m0, int n0,
                                          floatx4 acc[4][4]) {
  const int tid = threadIdx.x;
  const int wave = tid >> 6, lane = tid & 63;
  const int quad = lane >> 4, l16 = lane & 15;
  const int wm = (wave >> 1) * 64, wn = (wave & 1) * 64;
  const int srow = wave * 8 + (lane >> 3);
  const int scol = (((lane & 7) ^ ((lane >> 3) & 7)) * 8);
  const int lds_off = wave * 512 + lane * 8;
  const int swA = (l16 & 7);
  for (int k0 = 0; k0 < 2048; k0 += 64) {
    __syncthreads();
    #pragma unroll
    for (int c = 0; c < 4; c++) {
      gl_lds16(A + (size_t)(m0 + c * 32 + srow) * 2048 + k0 + scol, sA + c * 2048 + lds_off);
      gl_lds16(Bw + (size_t)(n0 + c * 32 + srow) * 2048 + k0 + scol, sB + c * 2048 + lds_off);
    }
    __syncthreads();
    #pragma unroll
    for (int ks = 0; ks < 64; ks += 32) {
      const int pc = ((((ks >> 3) + quad) ^ swA) << 3);
      bf16x8 af[4], bw[4];
      #pragma unroll
      for (int i = 0; i < 4; i++)
        af[i] = *(const bf16x8*)&sA[(wm + i * 16 + l16) * 64 + pc];
      #pragma unroll
      for (int j = 0; j < 4; j++)
        bw[j] = *(const bf16x8*)&sB[(wn + j * 16 + l16) * 64 + pc];
      #pragma unroll
      for (int i = 0; i < 4; i++)
        #pragma unroll
        for (int j = 0; j < 4; j++)
          acc[i][j] = __builtin_amdgcn_mfma_f32_16x16x32_bf16(af[i], bw[j], acc[i][j], 0, 0, 0);
    }
  }
}

// ---------------- fused QKV projection GEMM + fused RoPE epilogue ----------------
// R5-verified epilogue (70us): all lanes uniform; pair (even,odd col) in
// adjacent lanes; shfl_xor partner, each lane computes its own rotated element.
// q additionally scaled by (1/sqrt(128))*log2(e).
__global__ __launch_bounds__(256, 3) void gemm_qkv(const u16* __restrict__ xb,
                                                   const u16* __restrict__ wqb,
                                                   const u16* __restrict__ wkb,
                                                   const u16* __restrict__ wvb,
                                                   const float2* __restrict__ csnT,
                                                   u16* __restrict__ qb, u16* __restrict__ kb,
                                                   u16* __restrict__ vtb) {
  __shared__ __align__(16) u16 sA[128 * 64];
  __shared__ __align__(16) u16 sB[128 * 64];
  const int by = blockIdx.y;
  const u16* Bw; int n0, mode;
  if (by < 16)      { Bw = wqb; n0 = by * 128;        mode = 0; }
  else if (by < 20) { Bw = wkb; n0 = (by - 16) * 128; mode = 1; }
  else              { Bw = wvb; n0 = (by - 20) * 128; mode = 2; }
  const int m0 = blockIdx.x * 128;
  floatx4 acc[4][4] = {};
  gemm_core(xb, Bw, sA, sB, m0, n0, acc);
  const int tid = threadIdx.x;
  const int wave = tid >> 6, lane = tid & 63;
  const int quad = lane >> 4, l16 = lane & 15;
  const int wm = (wave >> 1) * 64, wn = (wave & 1) * 64;
  const float sgn = (l16 & 1) ? 1.0f : -1.0f;
  #pragma unroll
  for (int i = 0; i < 4; i++) {
    #pragma unroll
    for (int j = 0; j < 4; j++) {
      const int row0 = m0 + wm + i * 16 + quad * 4;
      const int col = n0 + wn + j * 16 + l16;
      const int p = ((wn + j * 16 + l16) & 127) >> 1;
      #pragma unroll
      for (int r = 0; r < 4; r++) {
        const int m = row0 + r;
        float val = acc[i][j][r];
        if (mode < 2) {  // fused RoPE (q and k)
          const float other = __shfl_xor(val, 1);
          const float2 cs = csnT[(m & 1023) * 64 + p];
          val = val * cs.x + sgn * other * cs.y;
          if (mode == 0) val *= 0.08838834764831845f * 1.4426950408889634f;
        }
        const u16 v16 = f2bf(val);
        if (mode == 0) {
          qb[(size_t)m * 2048 + col] = v16;
        } else if (mode == 1) {
          kb[(size_t)m * 512 + col] = v16;
        } else {
          int bb = m >> 10, sI = m & 1023, kvh = col >> 7, hd = col & 127;
          vtb[((size_t)((bb * 4 + kvh) * 128 + hd)) * 1024 + sI] = v16;
        }
      }
    }
  }
}

// ---------------- output projection GEMM (fp32 out) ----------------
__global__ __launch_bounds__(256, 3) void gemm_out(const u16* __restrict__ ob,
                                                   const u16* __restrict__ wob,
                                                   float* __restrict__ Cf) {
  __shared__ __align__(16) u16 sA[128 * 64];
  __shared__ __align__(16) u16 sB[128 * 64];
  const int m0 = blockIdx.x * 128, n0 = blockIdx.y * 128;
  floatx4 acc[4][4] = {};
  gemm_core(ob, wob, sA, sB, m0, n0, acc);
  const int tid = threadIdx.x;
  const int wave = tid >> 6, lane = tid & 63;
  const int quad = lane >> 4, l16 = lane & 15;
  const int wm = (wave >> 1) * 64, wn = (wave & 1) * 64;
  #pragma unroll
  for (int i = 0; i < 4; i++) {
    #pragma unroll
    for (int j = 0; j < 4; j++) {
      const int row0 = m0 + wm + i * 16 + quad * 4;
      const int col = n0 + wn + j * 16 + l16;
      #pragma unroll
      for (int r = 0; r < 4; r++)
        Cf[(size_t)(row0 + r) * 2048 + col] = acc[i][j][r];
    }
  }
}

// ---------------- O store: per-wave softmax-denominator normalize ----------------
__device__ __forceinline__ void store_out(u16* __restrict__ obaseHead, int qr0,
                                          floatx4 (&o_acc)[2][8], float (&l_part)[2],
                                          int quad, int l16) {
  #pragma unroll
  for (int i = 0; i < 2; i++) {
    float lr = l_part[i];
    lr += __shfl_xor(lr, 16);
    lr += __shfl_xor(lr, 32);
    #pragma unroll
    for (int r = 0; r < 4; r++) {
      const float inv = 1.f / __shfl(lr, quad * 4 + r);
      const int row = qr0 + i * 16 + quad * 4 + r;
      #pragma unroll
      for (int j = 0; j < 8; j++)
        obaseHead[(size_t)row * 2048 + j * 16 + l16] = f2bf(o_acc[i][j][r] * inv);
    }
  }
}

// ---------------- flash attention, LDS-staged K/V, counted-vmcnt (R8) ----------
// R3 structure + T4: V now double-buffered (LDS 80KB/block -> still exactly
// 2 blocks/CU = 160 KiB), both __syncthreads replaced by raw s_barrier with
// COUNTED s_waitcnt -- no full vmcnt(0) drains in the main loop, so the K[t+1]
// prefetch survives the mid-tile barrier and V[t+1] staging overlaps PV[t].
// Per-wave FIFO ledger (4 V-loads + 4 K-loads issued per tile):
//   top of tile t: outstanding = K(t):4 + V(t):4 + K(t+1):4  -> vmcnt(8) waits
//   K(t) (vmcnt(4) at t==m where no K(t+1) was issued); barrier -> all waves'
//   K(t) staged. After QK+softmax: vmcnt(4) leaves K(t+1) in flight (vmcnt(0)
//   at t==m); barrier -> all waves' V(t) staged. No end-of-tile barrier needed:
//   K(t+2)/V(t+1) writes target buffers whose readers all retired before the
//   V-ready barrier of tile t (re-derived; parities alternate).
// sched_barrier(0) after each asm waitcnt (rule #18); this asm pattern was
// HW-verified correct in R4.
__global__ __launch_bounds__(256)
__attribute__((amdgpu_waves_per_eu(2, 2)))
void flash_attn(const u16* __restrict__ q,
                const u16* __restrict__ k,
                const u16* __restrict__ vt,
                u16* __restrict__ o) {
  __shared__ __align__(16) u16 sK[2][64 * 128];  // 2 x 16 KB, chunk-swizzled
  __shared__ __align__(16) u16 sV[2][128 * 64];  // 2 x 16 KB (V^T)
  __shared__ __align__(16) u16 sP[4][32 * 64];   // per-wave P, 4 KB each
  const int tid = threadIdx.x;
  const int wave = tid >> 6, lane = tid & 63;
  const int quad = lane >> 4, l16 = lane & 15;
  const int bi = blockIdx.x;
  const int bkv = bi & 15;                 // b*4 + kv
  const int b = bkv >> 2, kv = bkv & 3;
  const int hp = (bi >> 4) & 1;            // which pair of the 4 GQA q-heads
  const int u = bi >> 5;                   // 0..15
  const int m = (u < 8) ? u : 23 - u;      // seq-block 0..15; pairs (m,15-m)/CU
  const int qh = kv * 4 + hp * 2 + (wave >> 1);
  const int qr0 = m * 64 + (wave & 1) * 32;

  const u16* qbase = q + (size_t)b * 2097152 + qh * 128;
  const u16* vbase = vt + (size_t)(b * 4 + kv) * 131072;
  u16* obase = o + (size_t)b * 2097152 + qh * 128;
  u16* myP = &sP[wave][0];

  // ---- Q fragments in registers (rows qr0+i*16+l16, k = ks*32+quad*8) ----
  bf16x8 aq[2][4];
  #pragma unroll
  for (int i = 0; i < 2; i++)
    #pragma unroll
    for (int ks = 0; ks < 4; ks++)
      aq[i][ks] = *(const bf16x8*)(qbase + (size_t)(qr0 + i * 16 + l16) * 2048 + ks * 32 + quad * 8);

  floatx4 o_acc[2][8];
  float l_part[2];
  const floatx4 vzero = {0.f, 0.f, 0.f, 0.f};
  #pragma unroll
  for (int i = 0; i < 2; i++) {
    l_part[i] = 0.f;
    #pragma unroll
    for (int j = 0; j < 8; j++) o_acc[i][j] = vzero;
  }

  // ---- staging helpers: 256 threads x 4 x 16B cover one 16 KB tile ----
  #define STAGE_K(T, PAR)                                                         \
    {                                                                             \
      const u16* kb_t = k + (size_t)(b * 1024 + (T) * 64) * 512 + kv * 128;       \
      _Pragma("unroll")                                                           \
      for (int v = 0; v < 4; v++) {                                               \
        int ci = v * 256 + tid;                                                   \
        int r = ci >> 4, c = ci & 15;                                             \
        gl_lds16(kb_t + r * 512 + ((c ^ (r & 7)) << 3), &sK[PAR][ci * 8]);        \
      }                                                                           \
    }
  #define STAGE_V(T, PAR)                                                         \
    {                                                                             \
      _Pragma("unroll")                                                           \
      for (int v = 0; v < 4; v++) {                                               \
        int ci = v * 256 + tid;                                                   \
        int r = ci >> 3, c = ci & 7;                                              \
        gl_lds16(vbase + r * 1024 + (T) * 64 + ((c ^ (r & 7)) << 3),              \
                 &sV[PAR][ci * 8]);                                               \
      }                                                                           \
    }

  STAGE_K(0, 0);

  for (int t = 0; t <= m; t++) {
    STAGE_V(t, t & 1);
    if (t < m) STAGE_K(t + 1, (t + 1) & 1);

    // K(t) ready: counted wait (K(t+1)+V(t) stay in flight), then barrier
    if (t < m) { asm volatile("s_waitcnt vmcnt(8)" ::: "memory"); }
    else       { asm volatile("s_waitcnt vmcnt(4)" ::: "memory"); }
    __builtin_amdgcn_sched_barrier(0);
    __builtin_amdgcn_s_barrier();

    // ---- S^T = K Q^T from LDS K buffer (1-deep fragment ping-pong) ----
    const u16* kcur = &sK[t & 1][0];
    floatx4 s_acc[4][2];
    #pragma unroll
    for (int j = 0; j < 4; j++)
      #pragma unroll
      for (int i = 0; i < 2; i++) s_acc[j][i] = vzero;
    bf16x8 bkA[4], bkB[4];
    #pragma unroll
    for (int j = 0; j < 4; j++) {
      const int R = j * 16 + l16;
      bkA[j] = *(const bf16x8*)&kcur[R * 128 + ((quad ^ (R & 7)) << 3)];
    }
    #pragma unroll
    for (int ks = 0; ks < 4; ks++) {
      bf16x8* cur = (ks & 1) ? bkB : bkA;
      bf16x8* nxt = (ks & 1) ? bkA : bkB;
      if (ks < 3) {
        #pragma unroll
        for (int j = 0; j < 4; j++) {
          const int R = j * 16 + l16;
          nxt[j] = *(const bf16x8*)&kcur[R * 128 + ((((ks + 1) * 4 + quad) ^ (R & 7)) << 3)];
        }
      }
      #pragma unroll
      for (int j = 0; j < 4; j++)
        #pragma unroll
        for (int i = 0; i < 2; i++)
          s_acc[j][i] = __builtin_amdgcn_mfma_f32_16x16x32_bf16(cur[j], aq[i][ks], s_acc[j][i], 0, 0, 0);
    }

    // ---- no-max softmax: p = exp2(s); mask only on the diagonal tile ----
    const bool nomask = (t < m);
    #pragma unroll
    for (int i = 0; i < 2; i++) {
      const int qrow = qr0 + i * 16 + l16;
      #pragma unroll
      for (int j = 0; j < 4; j++) {
        const int key0 = t * 64 + j * 16 + quad * 4;
        float e0, e1, e2, e3;
        if (nomask) {
          e0 = EXP2F(s_acc[j][i][0]);
          e1 = EXP2F(s_acc[j][i][1]);
          e2 = EXP2F(s_acc[j][i][2]);
          e3 = EXP2F(s_acc[j][i][3]);
        } else {
          e0 = (key0 + 0 <= qrow) ? EXP2F(s_acc[j][i][0]) : 0.f;
          e1 = (key0 + 1 <= qrow) ? EXP2F(s_acc[j][i][1]) : 0.f;
          e2 = (key0 + 2 <= qrow) ? EXP2F(s_acc[j][i][2]) : 0.f;
          e3 = (key0 + 3 <= qrow) ? EXP2F(s_acc[j][i][3]) : 0.f;
        }
        l_part[i] += (e0 + e1) + (e2 + e3);
        uint2 w;
        w.x = (u32)f2bf(e0) | ((u32)f2bf(e1) << 16);
        w.y = (u32)f2bf(e2) | ((u32)f2bf(e3) << 16);
        const int ri = i * 16 + l16;
        *(uint2*)&myP[ri * 64 + (((2 * j + (quad >> 1)) ^ (ri & 7)) << 3) + (quad & 1) * 4] = w;
      }
    }

    // V(t) ready: counted wait (K(t+1) stays in flight), then barrier
    if (t < m) { asm volatile("s_waitcnt vmcnt(4)" ::: "memory"); }
    else       { asm volatile("s_waitcnt vmcnt(0)" ::: "memory"); }
    __builtin_amdgcn_sched_barrier(0);
    __builtin_amdgcn_s_barrier();

    // ---- O += P V from LDS V buffer ----
    const u16* vcur = &sV[t & 1][0];
    #pragma unroll
    for (int ks2 = 0; ks2 < 2; ks2++) {
      bf16x8 ap[2], bvf[8];
      #pragma unroll
      for (int j2 = 0; j2 < 8; j2++) {
        const int R = j2 * 16 + l16;
        bvf[j2] = *(const bf16x8*)&vcur[R * 64 + (((ks2 * 4 + quad) ^ (R & 7)) << 3)];
      }
      #pragma unroll
      for (int i = 0; i < 2; i++) {
        const int ri = i * 16 + l16;
        ap[i] = *(const bf16x8*)&myP[ri * 64 + (((ks2 * 4 + quad) ^ (ri & 7)) << 3)];
      }
      #pragma unroll
      for (int i = 0; i < 2; i++)
        #pragma unroll
        for (int j2 = 0; j2 < 8; j2++)
          o_acc[i][j2] = __builtin_amdgcn_mfma_f32_16x16x32_bf16(ap[i], bvf[j2], o_acc[i][j2], 0, 0, 0);
    }
    // no end-of-tile barrier: next tile's stages write the other parity
    // buffers, whose readers all retired before this tile's V-ready barrier.
  }

  store_out(obase, qr0, o_acc, l_part, quad, l16);
  #undef STAGE_K
  #undef STAGE_V
}

extern "C" void kernel_launch(void* const* d_in, const int* in_sizes, int n_in,
                              void* d_out, int out_size, void* d_ws, size_t ws_size,
                              hipStream_t stream) {
  const float* x  = (const float*)d_in[0];
  const float* fr = (const float*)d_in[2];
  const float* wq = (const float*)d_in[4];
  const float* wk = (const float*)d_in[5];
  const float* wv = (const float*)d_in[6];
  const float* wo = (const float*)d_in[7];
  float* out = (float*)d_out;

  char* ws = (char*)d_ws;
  u16* xb  = (u16*)(ws + 0);           // 4096x2048        16.78 MB
  u16* wqb = (u16*)(ws + 16777216);    // 2048x2048         8.39 MB
  u16* wkb = (u16*)(ws + 25165824);    //  512x2048         2.10 MB
  u16* wvb = (u16*)(ws + 27262976);    //  512x2048         2.10 MB
  u16* wob = (u16*)(ws + 29360128);    // 2048x2048         8.39 MB
  u16* qb  = (u16*)(ws + 37748736);    // [B,S,16,128]     16.78 MB
  u16* kb  = (u16*)(ws + 54525952);    // [B,S,4,128]       4.19 MB
  u16* vtb = (u16*)(ws + 58720256);    // [B,4,128,S]       4.19 MB
  u16* ob  = (u16*)(ws + 62914560);    // [B,S,16,128]     16.78 MB
  // RoPE cos/sin table overlaps the FIRST 512 KB of ob: written by cvt_all,
  // read by gemm_qkv, and only AFTERWARDS does flash_attn overwrite ob.
  float2* csnT = (float2*)(ws + 62914560);

  cvt_all<<<18688, 256, 0, stream>>>(x, wq, wk, wv, wo, fr, xb, wqb, wkb, wvb, wob, csnT);
  gemm_qkv<<<dim3(32, 24), 256, 0, stream>>>(xb, wqb, wkb, wvb, csnT, qb, kb, vtb);
  flash_attn<<<512, 256, 0, stream>>>(qb, kb, vtb, ob);
  gemm_out<<<dim3(32, 16), 256, 0, stream>>>(ob, wob, out);
}